// Round 1
// baseline (164.120 us; speedup 1.0000x reference)
//
#include <hip/hip_runtime.h>
#include <math.h>

// DCNv2 forward: B=4, Cin=Cout=64, H=W=128, 3x3, stride=1, pad=1, dil=1, groups=dg=1
#define H_    128
#define W_    128
#define CIN_  64
#define COUT_ 64
#define K2_   9
#define P_    64   // output pixels per block (half a row)
#define B_    4

// Pre-transpose weight [Cout][Cin][9] -> wT [9][Cin][Cout] so per-k staging is coalesced.
__global__ __launch_bounds__(256) void wtrans_kernel(const float* __restrict__ w,
                                                     float* __restrict__ wt) {
    int idx = blockIdx.x * 256 + threadIdx.x;
    if (idx >= K2_ * CIN_ * COUT_) return;
    int k   = idx / (CIN_ * COUT_);
    int r   = idx % (CIN_ * COUT_);
    int cin = r >> 6;
    int co  = r & 63;
    wt[idx] = w[co * (CIN_ * K2_) + cin * K2_ + k];
}

__global__ __launch_bounds__(256) void dcn_kernel(
    const float* __restrict__ x,      // [B, Cin, H, W]
    const float* __restrict__ offset, // [B, 18, H, W]  (k*2 = y, k*2+1 = x)
    const float* __restrict__ mask,   // [B, 9, H, W]
    const float* __restrict__ wt,     // [9, Cin, Cout]  (transposed)
    const float* __restrict__ bias,   // [Cout]
    float* __restrict__ out)          // [B, Cout, H, W]
{
    __shared__ float s_samp[CIN_][P_];      // 16 KB  sampled values for current k
    __shared__ float s_w[CIN_ * COUT_];     // 16 KB  weight slice [cin][co] for current k

    const int tid  = threadIdx.x;
    const int lane = tid & 63;
    const int wave = tid >> 6;

    // block -> (b, ho, w0)
    const int bidx = blockIdx.x;
    const int b    = bidx >> 8;              // / (128*2)
    const int rem  = bidx & 255;
    const int ho   = rem >> 1;
    const int w0   = (rem & 1) * P_;
    const int wo   = w0 + lane;
    const int pix  = ho * W_ + wo;

    const float* xb   = x      + (size_t)b * CIN_ * H_ * W_;
    const float* offb = offset + (size_t)b * 2 * K2_ * H_ * W_;
    const float* mb   = mask   + (size_t)b * K2_ * H_ * W_;

    // GEMM register tile: 4 co x 4 px per thread
    const int pgroup  = tid & 15;   // pixel block: pgroup*4 .. +3
    const int cogroup = tid >> 4;   // cout block:  cogroup*4 .. +3

    float acc[4][4];
#pragma unroll
    for (int i = 0; i < 4; ++i)
#pragma unroll
        for (int j = 0; j < 4; ++j) acc[i][j] = 0.f;

#pragma unroll 1
    for (int k = 0; k < K2_; ++k) {
        // ---- per-lane sampling setup (per pixel, channel-independent) ----
        const int ky = k / 3, kx = k % 3;
        const float offy = offb[(2 * k)     * (H_ * W_) + pix];
        const float offx = offb[(2 * k + 1) * (H_ * W_) + pix];
        const float m    = mb[k * (H_ * W_) + pix];
        const float py = (float)(ho - 1 + ky) + offy;
        const float px = (float)(wo - 1 + kx) + offx;
        const float fy = floorf(py), fx = floorf(px);
        const int   y0 = (int)fy,    x0 = (int)fx;
        const float ly = py - fy,    lx = px - fx;
        const int   y1 = y0 + 1,     x1 = x0 + 1;

        const float vy0 = (y0 >= 0 && y0 < H_) ? 1.f : 0.f;
        const float vy1 = (y1 >= 0 && y1 < H_) ? 1.f : 0.f;
        const float vx0 = (x0 >= 0 && x0 < W_) ? 1.f : 0.f;
        const float vx1 = (x1 >= 0 && x1 < W_) ? 1.f : 0.f;
        const int cy0 = min(max(y0, 0), H_ - 1), cy1 = min(max(y1, 0), H_ - 1);
        const int cx0 = min(max(x0, 0), W_ - 1), cx1 = min(max(x1, 0), W_ - 1);
        const int i00 = cy0 * W_ + cx0, i01 = cy0 * W_ + cx1;
        const int i10 = cy1 * W_ + cx0, i11 = cy1 * W_ + cx1;

        // fold mask + validity into the 4 bilinear weights
        const float W00 = m * (1.f - ly) * (1.f - lx) * vy0 * vx0;
        const float W01 = m * (1.f - ly) * lx         * vy0 * vx1;
        const float W10 = m * ly * (1.f - lx)         * vy1 * vx0;
        const float W11 = m * ly * lx                 * vy1 * vx1;

        __syncthreads();  // previous GEMM finished reading s_samp / s_w

        // ---- sample this wave's 16 channels into LDS ----
        {
            const float* xc = xb + (size_t)(wave * 16) * (H_ * W_);
#pragma unroll
            for (int c = 0; c < 16; ++c) {
                const float* p = xc + (size_t)c * (H_ * W_);
                float v = W00 * p[i00] + W01 * p[i01] + W10 * p[i10] + W11 * p[i11];
                s_samp[wave * 16 + c][lane] = v;
            }
        }

        // ---- stage weight k-slice [cin][co], float4-coalesced ----
        {
            const float4* src = (const float4*)(wt + (size_t)k * (CIN_ * COUT_));
            float4*       dst = (float4*)s_w;
#pragma unroll
            for (int i = 0; i < 4; ++i)
                dst[i * 256 + tid] = src[i * 256 + tid];
        }

        __syncthreads();

        // ---- rank-64 update: acc[co 0..3][px 0..3] ----
#pragma unroll
        for (int cin = 0; cin < CIN_; ++cin) {
            const float4 sv = *(const float4*)&s_samp[cin][pgroup << 2];
            const float4 wv = *(const float4*)&s_w[(cin << 6) + (cogroup << 2)];
            acc[0][0] = fmaf(wv.x, sv.x, acc[0][0]);
            acc[0][1] = fmaf(wv.x, sv.y, acc[0][1]);
            acc[0][2] = fmaf(wv.x, sv.z, acc[0][2]);
            acc[0][3] = fmaf(wv.x, sv.w, acc[0][3]);
            acc[1][0] = fmaf(wv.y, sv.x, acc[1][0]);
            acc[1][1] = fmaf(wv.y, sv.y, acc[1][1]);
            acc[1][2] = fmaf(wv.y, sv.z, acc[1][2]);
            acc[1][3] = fmaf(wv.y, sv.w, acc[1][3]);
            acc[2][0] = fmaf(wv.z, sv.x, acc[2][0]);
            acc[2][1] = fmaf(wv.z, sv.y, acc[2][1]);
            acc[2][2] = fmaf(wv.z, sv.z, acc[2][2]);
            acc[2][3] = fmaf(wv.z, sv.w, acc[2][3]);
            acc[3][0] = fmaf(wv.w, sv.x, acc[3][0]);
            acc[3][1] = fmaf(wv.w, sv.y, acc[3][1]);
            acc[3][2] = fmaf(wv.w, sv.z, acc[3][2]);
            acc[3][3] = fmaf(wv.w, sv.w, acc[3][3]);
        }
    }

    // ---- epilogue: add bias, coalesced float4 stores ----
#pragma unroll
    for (int i = 0; i < 4; ++i) {
        const int co = cogroup * 4 + i;
        const float bv = bias[co];
        float4 o;
        o.x = acc[i][0] + bv;
        o.y = acc[i][1] + bv;
        o.z = acc[i][2] + bv;
        o.w = acc[i][3] + bv;
        *(float4*)&out[((size_t)(b * COUT_ + co)) * (H_ * W_) + ho * W_ + w0 + (pgroup << 2)] = o;
    }
}

extern "C" void kernel_launch(void* const* d_in, const int* in_sizes, int n_in,
                              void* d_out, int out_size, void* d_ws, size_t ws_size,
                              hipStream_t stream) {
    const float* x      = (const float*)d_in[0];
    const float* offset = (const float*)d_in[1];
    const float* mask   = (const float*)d_in[2];
    const float* weight = (const float*)d_in[3];
    const float* bias   = (const float*)d_in[4];
    float* out = (float*)d_out;
    float* wt  = (float*)d_ws;  // 9*64*64*4 = 147456 bytes

    // transpose weight -> [9][cin][cout]
    wtrans_kernel<<<(K2_ * CIN_ * COUT_ + 255) / 256, 256, 0, stream>>>(weight, wt);

    // main fused kernel: 1024 blocks (B * H * W/P_), 256 threads
    dcn_kernel<<<B_ * H_ * (W_ / P_), 256, 0, stream>>>(x, offset, mask, wt, bias, out);
}